// Round 1
// baseline (865.010 us; speedup 1.0000x reference)
//
#include <hip/hip_runtime.h>
#include <cstddef>

#define NB    4
#define CIN   32
#define COUT  64
#define NFINE 163842
#define NSV   40962
#define EPSB  1e-5f
#define SLOPE 0.2f

// ws layout (floats):
//   pooled [B][NS][CIN]      at P_POOL
//   h      [B][COUT][NS]     at P_H
//   stats  sum[64] sumsq[64] scale[64] shift[64]  at P_ST
#define P_POOL 0
#define P_H    ((size_t)NB * NSV * CIN)
#define P_ST   (P_H + (size_t)NB * COUT * NSV)

__global__ void k_zero(float* __restrict__ st) {
    st[threadIdx.x] = 0.f;   // 128 threads: sum + sumsq
}

__global__ __launch_bounds__(256) void k_pool(
        const float* __restrict__ x, const int* __restrict__ pool_neigh,
        float* __restrict__ pooled) {
    const int s = blockIdx.x * 256 + threadIdx.x;
    const int b = blockIdx.y;
    if (s >= NSV) return;
    int idx[7];
#pragma unroll
    for (int j = 0; j < 7; ++j) idx[j] = pool_neigh[7 * s + j];
    const float* xb = x + (size_t)b * CIN * NFINE;
    float acc[CIN];
#pragma unroll
    for (int c = 0; c < CIN; ++c) acc[c] = 0.f;
#pragma unroll
    for (int j = 0; j < 7; ++j) {
        const float* xj = xb + idx[j];
#pragma unroll
        for (int c = 0; c < CIN; ++c) acc[c] += xj[(size_t)c * NFINE];
    }
    float4* op = (float4*)(pooled + ((size_t)b * NSV + s) * CIN);
#pragma unroll
    for (int q = 0; q < CIN / 4; ++q) {
        op[q] = make_float4(acc[4*q+0] * (1.f/7.f), acc[4*q+1] * (1.f/7.f),
                            acc[4*q+2] * (1.f/7.f), acc[4*q+3] * (1.f/7.f));
    }
}

// h[b][o][s] = sum_{j,c} pooled[b][neigh[7s+j]][c] * W1[o][j*CIN+c] + b1[o]
// Also accumulates per-channel sum / sumsq for BN into stats buffer.
__global__ __launch_bounds__(256) void k_conv(
        const int* __restrict__ neigh, const float* __restrict__ W1,
        const float* __restrict__ b1, float* __restrict__ ws) {
    __shared__ __attribute__((aligned(16))) float W1s[7 * CIN * COUT]; // [k][o] 56KB
    __shared__ float b1s[COUT];
    __shared__ float red[2][4][COUT];

    for (int i = threadIdx.x; i < 7 * CIN * COUT; i += 256) {
        int o = i / (7 * CIN);
        int k = i - o * (7 * CIN);
        W1s[k * COUT + o] = W1[i];
    }
    if (threadIdx.x < COUT) b1s[threadIdx.x] = b1[threadIdx.x];
    __syncthreads();

    const int s = blockIdx.x * 256 + threadIdx.x;
    const int b = blockIdx.y;

    float acc[COUT];
#pragma unroll
    for (int o = 0; o < COUT; ++o) acc[o] = 0.f;

    if (s < NSV) {
        const float* pooled = ws + P_POOL + (size_t)b * NSV * CIN;
#pragma unroll
        for (int j = 0; j < 7; ++j) {
            const int t = neigh[7 * s + j];
            const float4* pv = (const float4*)(pooled + (size_t)t * CIN);
#pragma unroll
            for (int cq = 0; cq < CIN / 4; ++cq) {
                float4 v4 = pv[cq];
#pragma unroll
                for (int i4 = 0; i4 < 4; ++i4) {
                    float v = (i4 == 0) ? v4.x : (i4 == 1) ? v4.y : (i4 == 2) ? v4.z : v4.w;
                    const int k = j * CIN + cq * 4 + i4;
                    const float4* wrow = (const float4*)(W1s + k * COUT);
#pragma unroll
                    for (int oq = 0; oq < COUT / 4; ++oq) {
                        float4 w = wrow[oq];
                        acc[4*oq+0] += v * w.x;
                        acc[4*oq+1] += v * w.y;
                        acc[4*oq+2] += v * w.z;
                        acc[4*oq+3] += v * w.w;
                    }
                }
            }
        }
#pragma unroll
        for (int o = 0; o < COUT; ++o) acc[o] += b1s[o];
        float* hp = ws + P_H + (size_t)b * COUT * NSV + s;
#pragma unroll
        for (int o = 0; o < COUT; ++o) hp[(size_t)o * NSV] = acc[o];
    }
    // BN partial stats: inactive threads hold acc==0 (no b1 added) -> contribute 0.
    const int wave = threadIdx.x >> 6, lane = threadIdx.x & 63;
#pragma unroll
    for (int o = 0; o < COUT; ++o) {
        float v = (s < NSV) ? acc[o] : 0.f;
        float v2 = v * v;
#pragma unroll
        for (int off = 32; off; off >>= 1) {
            v  += __shfl_xor(v,  off);
            v2 += __shfl_xor(v2, off);
        }
        if (lane == 0) { red[0][wave][o] = v; red[1][wave][o] = v2; }
    }
    __syncthreads();
    if (threadIdx.x < COUT) {
        const int o = threadIdx.x;
        float s0 = red[0][0][o] + red[0][1][o] + red[0][2][o] + red[0][3][o];
        float s1 = red[1][0][o] + red[1][1][o] + red[1][2][o] + red[1][3][o];
        atomicAdd(ws + P_ST + o, s0);
        atomicAdd(ws + P_ST + COUT + o, s1);
    }
}

__global__ void k_stats(const float* __restrict__ gamma,
                        const float* __restrict__ beta, float* __restrict__ ws) {
    const int o = threadIdx.x;  // 64
    const float cnt = (float)((size_t)NB * NSV);
    float mu  = ws[P_ST + o] / cnt;
    float var = ws[P_ST + COUT + o] / cnt - mu * mu;
    float sc  = gamma[o] * rsqrtf(var + EPSB);
    ws[P_ST + 2 * COUT + o] = sc;
    ws[P_ST + 3 * COUT + o] = beta[o] - mu * sc;
}

// out[b][o][s] = sum_c leaky(scale[c]*h[b][c][s]+shift[c]) * Wc[o][c]
//             + sum_c x1[b][c][s] * Wc[o][COUT+c] + bc[o]
__global__ __launch_bounds__(256) void k_out(
        const float* __restrict__ x1, const float* __restrict__ Wc,
        const float* __restrict__ bc, const float* __restrict__ ws,
        float* __restrict__ out) {
    __shared__ __attribute__((aligned(16))) float Wcs[2 * COUT * COUT]; // [c2][o] 32KB
    __shared__ float scs[COUT], shs[COUT], bcs[COUT];

    for (int i = threadIdx.x; i < 2 * COUT * COUT; i += 256) {
        int o = i >> 7, c2 = i & 127;
        Wcs[c2 * COUT + o] = Wc[i];
    }
    if (threadIdx.x < COUT) {
        scs[threadIdx.x] = ws[P_ST + 2 * COUT + threadIdx.x];
        shs[threadIdx.x] = ws[P_ST + 3 * COUT + threadIdx.x];
        bcs[threadIdx.x] = bc[threadIdx.x];
    }
    __syncthreads();

    const int s = blockIdx.x * 256 + threadIdx.x;
    const int b = blockIdx.y;
    if (s >= NSV) return;

    float acc[COUT];
#pragma unroll
    for (int o = 0; o < COUT; ++o) acc[o] = 0.f;

    const float* hp = ws + P_H + (size_t)b * COUT * NSV + s;
#pragma unroll
    for (int c = 0; c < COUT; ++c) {
        float v = scs[c] * hp[(size_t)c * NSV] + shs[c];
        v = (v >= 0.f) ? v : SLOPE * v;
        const float4* wrow = (const float4*)(Wcs + c * COUT);
#pragma unroll
        for (int oq = 0; oq < COUT / 4; ++oq) {
            float4 w = wrow[oq];
            acc[4*oq+0] += v * w.x;
            acc[4*oq+1] += v * w.y;
            acc[4*oq+2] += v * w.z;
            acc[4*oq+3] += v * w.w;
        }
    }
    const float* x1p = x1 + (size_t)b * COUT * NSV + s;
#pragma unroll
    for (int c = 0; c < COUT; ++c) {
        float v = x1p[(size_t)c * NSV];
        const float4* wrow = (const float4*)(Wcs + (COUT + c) * COUT);
#pragma unroll
        for (int oq = 0; oq < COUT / 4; ++oq) {
            float4 w = wrow[oq];
            acc[4*oq+0] += v * w.x;
            acc[4*oq+1] += v * w.y;
            acc[4*oq+2] += v * w.z;
            acc[4*oq+3] += v * w.w;
        }
    }
    float* op = out + (size_t)b * COUT * NSV + s;
#pragma unroll
    for (int o = 0; o < COUT; ++o) op[(size_t)o * NSV] = acc[o] + bcs[o];
}

extern "C" void kernel_launch(void* const* d_in, const int* in_sizes, int n_in,
                              void* d_out, int out_size, void* d_ws, size_t ws_size,
                              hipStream_t stream) {
    const float* x          = (const float*)d_in[0];
    const float* x1         = (const float*)d_in[1];
    const int*   pool_neigh = (const int*)d_in[2];
    const int*   neigh      = (const int*)d_in[3];
    const float* W1         = (const float*)d_in[4];
    const float* b1         = (const float*)d_in[5];
    const float* gamma      = (const float*)d_in[6];
    const float* beta       = (const float*)d_in[7];
    const float* Wc         = (const float*)d_in[8];
    const float* bc         = (const float*)d_in[9];
    float* ws  = (float*)d_ws;
    float* out = (float*)d_out;

    dim3 grid((NSV + 255) / 256, NB);

    k_zero<<<1, 128, 0, stream>>>(ws + P_ST);
    k_pool<<<grid, 256, 0, stream>>>(x, pool_neigh, ws + P_POOL);
    k_conv<<<grid, 256, 0, stream>>>(neigh, W1, b1, ws);
    k_stats<<<1, 64, 0, stream>>>(gamma, beta, ws);
    k_out<<<grid, 256, 0, stream>>>(x1, Wc, bc, ws, out);
}